// Round 8
// baseline (1674.745 us; speedup 1.0000x reference)
//
#include <hip/hip_runtime.h>
#include <hip/hip_bf16.h>
#include <math.h>

#define HC 64
#define DD 128
#define NPB 32      // nodes per block in node_transform (4 waves x 8 nodes)
#define BSH 7       // bucket = 128 consecutive ids
#define BW  128
#define KMAX 512    // max buckets; ids must fit 16 bits (N <= 65536)
#define CHUNK 4096  // edges per partition/hist workgroup
#define CH2 256     // edges per bucket_message chunk

// ---------------- node transform (both graphs in one grid) ----------------
// xs = elu(x)@Wsrc (bf16); logits PRESCALED by log2(e) for hw exp2
// (leaky_relu is positively homogeneous: leaky(c*a)=c*leaky(a), c>0).
__global__ __launch_bounds__(256) void node_transform2(
    const float* __restrict__ xH, const float* __restrict__ xT,
    const float* __restrict__ Wsrc, const float* __restrict__ Wdst,
    const float* __restrict__ att_src, const float* __restrict__ att_dst,
    __hip_bfloat16* __restrict__ xsH, __hip_bfloat16* __restrict__ xsT,
    float* __restrict__ lsH, float* __restrict__ ldH,
    float* __restrict__ lsT, float* __restrict__ ldT,
    int NH, int NT, int blocksH)
{
  const float* x; __hip_bfloat16* xs_out; float* logit_s; float* logit_d;
  int N, blk;
  if ((int)blockIdx.x < blocksH) { x = xH; xs_out = xsH; logit_s = lsH; logit_d = ldH; N = NH; blk = blockIdx.x; }
  else { x = xT; xs_out = xsT; logit_s = lsT; logit_d = ldT; N = NT; blk = blockIdx.x - blocksH; }

  __shared__ float sx[NPB * DD];       // 16 KB
  int tid = threadIdx.x;
  int nbase = blk * NPB;
  for (int i = tid; i < NPB * DD; i += 256) {
    int n = nbase + (i >> 7);
    float v = 0.f;
    if (n < N) {
      v = x[(size_t)n * DD + (i & 127)];
      v = (v > 0.f) ? v : (exp2f(v * 1.44269504f) - 1.f);   // elu
    }
    sx[i] = v;
  }
  __syncthreads();

  const float LOG2E = 1.44269504f;
  int j = tid & 63;
  int wid = tid >> 6;
  float as = att_src[j] * LOG2E;
  float ad = att_dst[j] * LOG2E;

  float accs[8], accd[8];
  #pragma unroll
  for (int m = 0; m < 8; ++m) { accs[m] = 0.f; accd[m] = 0.f; }

  const float* xbase = &sx[wid * 8 * DD];
  for (int k = 0; k < DD; k += 4) {
    float ws[4], wd[4];
    #pragma unroll
    for (int kk = 0; kk < 4; ++kk) {
      ws[kk] = Wsrc[(k + kk) * HC + j];
      wd[kk] = Wdst[(k + kk) * HC + j];
    }
    #pragma unroll
    for (int m = 0; m < 8; ++m) {
      const float4 xv = *(const float4*)&xbase[m * DD + k];
      accs[m] = fmaf(xv.x, ws[0], accs[m]);
      accd[m] = fmaf(xv.x, wd[0], accd[m]);
      accs[m] = fmaf(xv.y, ws[1], accs[m]);
      accd[m] = fmaf(xv.y, wd[1], accd[m]);
      accs[m] = fmaf(xv.z, ws[2], accs[m]);
      accd[m] = fmaf(xv.z, wd[2], accd[m]);
      accs[m] = fmaf(xv.w, ws[3], accs[m]);
      accd[m] = fmaf(xv.w, wd[3], accd[m]);
    }
  }

  #pragma unroll
  for (int m = 0; m < 8; ++m) {
    int n = nbase + wid * 8 + m;
    if (n >= N) break;
    xs_out[(size_t)n * HC + j] = __float2bfloat16(accs[m]);
    float ps = accs[m] * as;
    float pd = accd[m] * ad;
    #pragma unroll
    for (int off = 16; off > 0; off >>= 1) {
      ps += __shfl_xor(ps, off, 64);
      pd += __shfl_xor(pd, off, 64);
    }
    if ((j & 31) == 0) {
      int h = j >> 5;
      logit_s[n * 2 + h] = ps;
      logit_d[n * 2 + h] = pd;
    }
  }
}

// ---------------- counting sort (bucket granularity only) ----------------
__global__ __launch_bounds__(256) void hist_both(
    const int* __restrict__ src, const int* __restrict__ dst, int E, int NL,
    int* __restrict__ histA, int* __restrict__ histB, int KA, int KB, int B)
{
  __shared__ int hA[KMAX];
  __shared__ int hB[KMAX];
  int tid = threadIdx.x, bid = blockIdx.x;
  for (int i = tid; i < KA; i += 256) hA[i] = 0;
  for (int i = tid; i < KB; i += 256) hB[i] = 0;
  __syncthreads();
  int base = bid * CHUNK;
  int E2 = E + NL;
  int lim = base + CHUNK < E2 ? base + CHUNK : E2;
  for (int i = base + tid; i < lim; i += 256) {
    int s, d;
    if (i < E) { s = src[i]; d = dst[i]; } else { s = d = i - E; }
    atomicAdd(&hA[d >> BSH], 1);
    atomicAdd(&hB[s >> BSH], 1);
  }
  __syncthreads();
  for (int k = tid; k < KA; k += 256) histA[(size_t)k * B + bid] = hA[k];
  for (int k = tid; k < KB; k += 256) histB[(size_t)k * B + bid] = hB[k];
}

// one WAVE per bucket: exclusive scan of its B chunk counts; emit totals
__global__ __launch_bounds__(256) void scan_hist(
    int* __restrict__ histA, int KA, int* __restrict__ histB, int KB, int B,
    int* __restrict__ totals)
{
  int j = blockIdx.x * 4 + (threadIdx.x >> 6);
  if (j >= KA + KB) return;
  int lane = threadIdx.x & 63;
  int* rowp = (j < KA) ? &histA[(size_t)j * B] : &histB[(size_t)(j - KA) * B];
  int carry = 0;
  for (int c0 = 0; c0 < B; c0 += 64) {
    int c = c0 + lane;
    int v = (c < B) ? rowp[c] : 0;
    int inc = v;
    #pragma unroll
    for (int off = 1; off < 64; off <<= 1) {
      int u = __shfl_up(inc, off, 64);
      if (lane >= off) inc += u;
    }
    if (c < B) rowp[c] = inc - v + carry;
    carry += __shfl(inc, 63, 64);
  }
  if (lane == 0) totals[j] = carry;
}

__global__ __launch_bounds__(1024) void scan_totals(
    const int* __restrict__ totals, int KA, int KB, int E2,
    int* __restrict__ offA, int* __restrict__ offB)
{
  __shared__ int buf[1024];
  int t = threadIdx.x;
  int v = (t < KA) ? totals[t] : 0;
  buf[t] = v; __syncthreads();
  #pragma unroll
  for (int off = 1; off < 1024; off <<= 1) {
    int u = (t >= off) ? buf[t - off] : 0;
    __syncthreads(); buf[t] += u; __syncthreads();
  }
  if (t < KA) offA[t] = buf[t] - v;
  if (t == 0) offA[KA] = E2;
  __syncthreads();
  int v2 = (t < KB) ? totals[KA + t] : 0;
  buf[t] = v2; __syncthreads();
  #pragma unroll
  for (int off = 1; off < 1024; off <<= 1) {
    int u = (t >= off) ? buf[t - off] : 0;
    __syncthreads(); buf[t] += u; __syncthreads();
  }
  if (t < KB) offB[t] = buf[t] - v2;
  if (t == 0) offB[KB] = E2;
}

// partition into bucket-contiguous segments. word = other | (key << 16),
// full 16-bit key -> bucket recovered as w >> 23 (no search).
// blockIdx.y: 0 = pass A (key=dst), 1 = pass B (key=src)
__global__ __launch_bounds__(256) void partition_edges(
    const int* __restrict__ src, const int* __restrict__ dst, int E, int NL,
    const int* __restrict__ histA, const int* __restrict__ offA,
    const int* __restrict__ histB, const int* __restrict__ offB,
    unsigned int* __restrict__ partA, unsigned int* __restrict__ partB,
    int KA, int KB, int B)
{
  __shared__ unsigned int stage[CHUNK];  // 16 KB
  __shared__ int lbase[KMAX];
  __shared__ int lcur[KMAX];
  __shared__ int gbase[KMAX];
  int tid = threadIdx.x, bid = blockIdx.x;
  int pass = blockIdx.y;
  const int K = pass ? KB : KA;
  const int* hist = pass ? histB : histA;
  const int* off  = pass ? offB : offA;
  unsigned int* out = pass ? partB : partA;

  int base = bid * CHUNK;
  int E2 = E + NL;
  int lim = base + CHUNK < E2 ? base + CHUNK : E2;
  int cnt = lim - base;

  for (int i = tid; i < K; i += 256) lbase[i] = 0;
  __syncthreads();
  for (int i = base + tid; i < lim; i += 256) {
    int s, d;
    if (i < E) { s = src[i]; d = dst[i]; } else { s = d = i - E; }
    int key = pass ? s : d;
    atomicAdd(&lbase[key >> BSH], 1);
  }
  __syncthreads();
  if (tid < 64) {                      // wave-0 exclusive scan over K counts
    int carry = 0;
    for (int c0 = 0; c0 < K; c0 += 64) {
      int c = c0 + tid;
      int v = (c < K) ? lbase[c] : 0;
      int inc = v;
      #pragma unroll
      for (int o = 1; o < 64; o <<= 1) {
        int u = __shfl_up(inc, o, 64);
        if (tid >= o) inc += u;
      }
      if (c < K) lbase[c] = inc - v + carry;
      carry += __shfl(inc, 63, 64);
    }
  }
  __syncthreads();
  for (int k = tid; k < K; k += 256) {
    lcur[k] = lbase[k];
    gbase[k] = off[k] + hist[(size_t)k * B + bid];
  }
  __syncthreads();
  for (int i = base + tid; i < lim; i += 256) {
    int s, d;
    if (i < E) { s = src[i]; d = dst[i]; } else { s = d = i - E; }
    int key = pass ? s : d;
    int val = pass ? d : s;
    int pos = atomicAdd(&lcur[key >> BSH], 1);
    stage[pos] = (unsigned int)val | ((unsigned int)key << 16);
  }
  __syncthreads();
  for (int i = tid; i < cnt; i += 256) {
    unsigned int wv = stage[i];
    int k = wv >> (16 + BSH);
    out[gbase[k] + (i - lbase[k])] = wv;
  }
}

// ---------------- fused softmax+message: one block per bucket ----------------
__device__ __forceinline__ float lrelu_clamp(float a) {
  a = (a > 0.f) ? a : 0.2f * a;
  return fminf(a, 43.f);
}

__global__ __launch_bounds__(256) void bucket_message(
    const unsigned int* __restrict__ partA, const int* __restrict__ offA, int KA,
    const float* __restrict__ lsA, const float* __restrict__ ldA,
    const __hip_bfloat16* __restrict__ xsA, float* __restrict__ outA, int NA,
    const unsigned int* __restrict__ partB, const int* __restrict__ offB,
    const float* __restrict__ lsB, const float* __restrict__ ldB,
    const __hip_bfloat16* __restrict__ xsB, float* __restrict__ outB, int NB,
    const float* __restrict__ bias)
{
  __shared__ float acc[BW * HC];      // 32 KB
  __shared__ float denom[BW * 2];     // 1 KB
  __shared__ float ldc[BW * 2];       // 1 KB (bucket's logit_d cache)
  __shared__ unsigned int sidx[CH2];  // 1 KB
  __shared__ float sew[2][CH2];       // 2 KB

  const unsigned int* part; const int* off; const float* ls; const float* ld;
  const __hip_bfloat16* xs; float* out; int k, N;
  if ((int)blockIdx.x < KA) { k = blockIdx.x; part = partA; off = offA; ls = lsA; ld = ldA; xs = xsA; out = outA; N = NA; }
  else { k = blockIdx.x - KA; part = partB; off = offB; ls = lsB; ld = ldB; xs = xsB; out = outB; N = NB; }

  int tid = threadIdx.x;
  int lane = tid & 63;
  int wv = tid >> 6;
  int h = lane >> 5;
  int d0 = k << BSH;
  int width = (BW < N - d0) ? BW : (N - d0);

  for (int i = tid; i < BW * HC; i += 256) acc[i] = 0.f;
  if (tid < BW * 2) denom[tid] = 0.f;
  if (tid < width * 2) ldc[tid] = ld[d0 * 2 + tid];
  __syncthreads();

  int beg = off[k], end = off[k + 1];
  for (int c0 = beg; c0 < end; c0 += CH2) {
    int cnt = (CH2 < end - c0) ? CH2 : (end - c0);
    // phase A: one edge per thread — weights computed ONCE per edge
    if (tid < cnt) {
      unsigned int wrd = part[c0 + tid];
      int s  = wrd & 0xFFFF;
      int dl = (wrd >> 16) & (BW - 1);
      float2 l2 = ((const float2*)ls)[s];
      float e0 = exp2f(lrelu_clamp(l2.x + ldc[dl * 2 + 0]));
      float e1 = exp2f(lrelu_clamp(l2.y + ldc[dl * 2 + 1]));
      atomicAdd(&denom[dl * 2 + 0], e0);
      atomicAdd(&denom[dl * 2 + 1], e1);
      sidx[tid] = wrd;
      sew[0][tid] = e0;
      sew[1][tid] = e1;
    }
    __syncthreads();
    // phase B: wave-per-edge accumulate (just LDS reads + gather + fma + ds_add)
    int jbeg = wv * 64;
    int jend = jbeg + 64 < cnt ? jbeg + 64 : cnt;
    int j = jbeg;
    for (; j + 4 <= jend; j += 4) {
      unsigned int wa = sidx[j], wb2 = sidx[j + 1], wc = sidx[j + 2], wd = sidx[j + 3];
      float ea = sew[h][j], eb = sew[h][j + 1], ec = sew[h][j + 2], ed = sew[h][j + 3];
      float xa = __bfloat162float(xs[(size_t)(wa & 0xFFFF) * HC + lane]);
      float xb = __bfloat162float(xs[(size_t)(wb2 & 0xFFFF) * HC + lane]);
      float xc = __bfloat162float(xs[(size_t)(wc & 0xFFFF) * HC + lane]);
      float xd = __bfloat162float(xs[(size_t)(wd & 0xFFFF) * HC + lane]);
      atomicAdd(&acc[((wa >> 16) & (BW - 1)) * HC + lane], ea * xa);
      atomicAdd(&acc[((wb2 >> 16) & (BW - 1)) * HC + lane], eb * xb);
      atomicAdd(&acc[((wc >> 16) & (BW - 1)) * HC + lane], ec * xc);
      atomicAdd(&acc[((wd >> 16) & (BW - 1)) * HC + lane], ed * xd);
    }
    for (; j < jend; ++j) {
      unsigned int wa = sidx[j];
      float ea = sew[h][j];
      float xa = __bfloat162float(xs[(size_t)(wa & 0xFFFF) * HC + lane]);
      atomicAdd(&acc[((wa >> 16) & (BW - 1)) * HC + lane], ea * xa);
    }
    __syncthreads();
  }

  // writeout: out = acc / denom + bias
  for (int i = tid; i < width * HC; i += 256) {
    int dl = i >> 6, c = i & 63, hh = c >> 5;
    out[(size_t)(d0 + dl) * HC + c] =
        acc[i] / (denom[dl * 2 + hh] + 1e-16f) + bias[c];
  }
}

extern "C" void kernel_launch(void* const* d_in, const int* in_sizes, int n_in,
                              void* d_out, int out_size, void* d_ws, size_t ws_size,
                              hipStream_t stream)
{
  const float* h_x   = (const float*)d_in[0];
  const float* t_x   = (const float*)d_in[1];
  const int*   edge  = (const int*)d_in[2];
  const float* W_src = (const float*)d_in[3];
  const float* W_dst = (const float*)d_in[4];
  const float* att_s = (const float*)d_in[5];
  const float* att_d = (const float*)d_in[6];
  const float* bias  = (const float*)d_in[7];

  int NH = in_sizes[0] / DD;
  int NT = in_sizes[1] / DD;
  int E  = in_sizes[2] / 2;
  int NL = (NH < NT) ? NH : NT;
  int E2 = E + NL;
  const int* srcA = edge;       // row 0 (h index)
  const int* dstA = edge + E;   // row 1 (t index)

  int KA = (NT + BW - 1) >> BSH;   // pass A buckets (over t / dst)
  int KB = (NH + BW - 1) >> BSH;   // pass B buckets (over h / src)
  int B  = (E2 + CHUNK - 1) / CHUNK;

  char* w = (char*)d_ws;
  size_t used = 0;
  auto alloc = [&](size_t bytes) {
    char* p = w + used; used = (used + bytes + 255) & ~(size_t)255; return p;
  };
  __hip_bfloat16* xsA = (__hip_bfloat16*)alloc((size_t)NH * HC * 2);
  __hip_bfloat16* xsB = (__hip_bfloat16*)alloc((size_t)NT * HC * 2);
  float* lsA  = (float*)alloc((size_t)NH * 2 * 4);
  float* ldB  = (float*)alloc((size_t)NH * 2 * 4);
  float* lsB  = (float*)alloc((size_t)NT * 2 * 4);
  float* ldA  = (float*)alloc((size_t)NT * 2 * 4);
  int* histA  = (int*)alloc((size_t)KA * B * 4);
  int* histB  = (int*)alloc((size_t)KB * B * 4);
  int* totals = (int*)alloc((size_t)(KA + KB) * 4);
  int* offA   = (int*)alloc((size_t)(KA + 1) * 4);
  int* offB   = (int*)alloc((size_t)(KB + 1) * 4);
  unsigned int* partA = (unsigned int*)alloc((size_t)E2 * 4);
  unsigned int* partB = (unsigned int*)alloc((size_t)E2 * 4);

  float* out   = (float*)d_out;              // (h_rep [NH,64], t_rep [NT,64])
  float* out_h = out;
  float* out_t = out + (size_t)NH * HC;

  int bH = (NH + NPB - 1) / NPB, bT = (NT + NPB - 1) / NPB;
  node_transform2<<<bH + bT, 256, 0, stream>>>(
      h_x, t_x, W_src, W_dst, att_s, att_d,
      xsA, xsB, lsA, ldB, lsB, ldA, NH, NT, bH);

  hist_both<<<B, 256, 0, stream>>>(srcA, dstA, E, NL, histA, histB, KA, KB, B);
  scan_hist<<<(KA + KB + 3) / 4, 256, 0, stream>>>(histA, KA, histB, KB, B, totals);
  scan_totals<<<1, 1024, 0, stream>>>(totals, KA, KB, E2, offA, offB);
  partition_edges<<<dim3(B, 2), 256, 0, stream>>>(
      srcA, dstA, E, NL, histA, offA, histB, offB, partA, partB, KA, KB, B);

  // pass A: src=h, dst=t -> t_rep ; pass B: src=t, dst=h -> h_rep
  bucket_message<<<KA + KB, 256, 0, stream>>>(
      partA, offA, KA, lsA, ldA, xsA, out_t, NT,
      partB, offB, lsB, ldB, xsB, out_h, NH, bias);
}

// Round 9
// 318.113 us; speedup vs baseline: 5.2646x; 5.2646x over previous
//
#include <hip/hip_runtime.h>
#include <hip/hip_bf16.h>
#include <math.h>

#define HC 64
#define DD 128
#define NPB 32      // nodes per block in node_transform (4 waves x 8 nodes)
#define BSH 7       // bucket = 128 consecutive ids
#define BW  128
#define KMAX 512    // max buckets; ids must fit 16 bits (N <= 65536)
#define CHUNK 4096  // edges per partition/hist workgroup
#define CAP 8192    // LDS sort capacity in bucket_csr (entries)

// ---------------- node transform (both graphs in one grid) ----------------
// xs = elu(x)@Wsrc (bf16); logits PRESCALED by log2(e) for hw exp2
// (leaky_relu is positively homogeneous: leaky(c*a)=c*leaky(a), c>0).
__global__ __launch_bounds__(256) void node_transform2(
    const float* __restrict__ xH, const float* __restrict__ xT,
    const float* __restrict__ Wsrc, const float* __restrict__ Wdst,
    const float* __restrict__ att_src, const float* __restrict__ att_dst,
    __hip_bfloat16* __restrict__ xsH, __hip_bfloat16* __restrict__ xsT,
    float* __restrict__ lsH, float* __restrict__ ldH,
    float* __restrict__ lsT, float* __restrict__ ldT,
    int NH, int NT, int blocksH)
{
  const float* x; __hip_bfloat16* xs_out; float* logit_s; float* logit_d;
  int N, blk;
  if ((int)blockIdx.x < blocksH) { x = xH; xs_out = xsH; logit_s = lsH; logit_d = ldH; N = NH; blk = blockIdx.x; }
  else { x = xT; xs_out = xsT; logit_s = lsT; logit_d = ldT; N = NT; blk = blockIdx.x - blocksH; }

  __shared__ float sx[NPB * DD];       // 16 KB
  int tid = threadIdx.x;
  int nbase = blk * NPB;
  for (int i = tid; i < NPB * DD; i += 256) {
    int n = nbase + (i >> 7);
    float v = 0.f;
    if (n < N) {
      v = x[(size_t)n * DD + (i & 127)];
      v = (v > 0.f) ? v : (exp2f(v * 1.44269504f) - 1.f);   // elu
    }
    sx[i] = v;
  }
  __syncthreads();

  const float LOG2E = 1.44269504f;
  int j = tid & 63;
  int wid = tid >> 6;
  float as = att_src[j] * LOG2E;
  float ad = att_dst[j] * LOG2E;

  float accs[8], accd[8];
  #pragma unroll
  for (int m = 0; m < 8; ++m) { accs[m] = 0.f; accd[m] = 0.f; }

  const float* xbase = &sx[wid * 8 * DD];
  for (int k = 0; k < DD; k += 4) {
    float ws[4], wd[4];
    #pragma unroll
    for (int kk = 0; kk < 4; ++kk) {
      ws[kk] = Wsrc[(k + kk) * HC + j];
      wd[kk] = Wdst[(k + kk) * HC + j];
    }
    #pragma unroll
    for (int m = 0; m < 8; ++m) {
      const float4 xv = *(const float4*)&xbase[m * DD + k];
      accs[m] = fmaf(xv.x, ws[0], accs[m]);
      accd[m] = fmaf(xv.x, wd[0], accd[m]);
      accs[m] = fmaf(xv.y, ws[1], accs[m]);
      accd[m] = fmaf(xv.y, wd[1], accd[m]);
      accs[m] = fmaf(xv.z, ws[2], accs[m]);
      accd[m] = fmaf(xv.z, wd[2], accd[m]);
      accs[m] = fmaf(xv.w, ws[3], accs[m]);
      accd[m] = fmaf(xv.w, wd[3], accd[m]);
    }
  }

  #pragma unroll
  for (int m = 0; m < 8; ++m) {
    int n = nbase + wid * 8 + m;
    if (n >= N) break;
    xs_out[(size_t)n * HC + j] = __float2bfloat16(accs[m]);
    float ps = accs[m] * as;
    float pd = accd[m] * ad;
    #pragma unroll
    for (int off = 16; off > 0; off >>= 1) {
      ps += __shfl_xor(ps, off, 64);
      pd += __shfl_xor(pd, off, 64);
    }
    if ((j & 31) == 0) {
      int h = j >> 5;
      logit_s[n * 2 + h] = ps;
      logit_d[n * 2 + h] = pd;
    }
  }
}

// ---------------- counting sort ----------------
__global__ __launch_bounds__(256) void hist_both(
    const int* __restrict__ src, const int* __restrict__ dst, int E, int NL,
    int* __restrict__ histA, int* __restrict__ histB, int KA, int KB, int B)
{
  __shared__ int hA[KMAX];
  __shared__ int hB[KMAX];
  int tid = threadIdx.x, bid = blockIdx.x;
  for (int i = tid; i < KA; i += 256) hA[i] = 0;
  for (int i = tid; i < KB; i += 256) hB[i] = 0;
  __syncthreads();
  int base = bid * CHUNK;
  int E2 = E + NL;
  int lim = base + CHUNK < E2 ? base + CHUNK : E2;
  for (int i = base + tid; i < lim; i += 256) {
    int s, d;
    if (i < E) { s = src[i]; d = dst[i]; } else { s = d = i - E; }
    atomicAdd(&hA[d >> BSH], 1);
    atomicAdd(&hB[s >> BSH], 1);
  }
  __syncthreads();
  for (int k = tid; k < KA; k += 256) histA[(size_t)k * B + bid] = hA[k];
  for (int k = tid; k < KB; k += 256) histB[(size_t)k * B + bid] = hB[k];
}

// one WAVE per bucket: exclusive scan of its B chunk counts; emit totals
__global__ __launch_bounds__(256) void scan_hist(
    int* __restrict__ histA, int KA, int* __restrict__ histB, int KB, int B,
    int* __restrict__ totals)
{
  int j = blockIdx.x * 4 + (threadIdx.x >> 6);
  if (j >= KA + KB) return;
  int lane = threadIdx.x & 63;
  int* rowp = (j < KA) ? &histA[(size_t)j * B] : &histB[(size_t)(j - KA) * B];
  int carry = 0;
  for (int c0 = 0; c0 < B; c0 += 64) {
    int c = c0 + lane;
    int v = (c < B) ? rowp[c] : 0;
    int inc = v;
    #pragma unroll
    for (int off = 1; off < 64; off <<= 1) {
      int u = __shfl_up(inc, off, 64);
      if (lane >= off) inc += u;
    }
    if (c < B) rowp[c] = inc - v + carry;
    carry += __shfl(inc, 63, 64);
  }
  if (lane == 0) totals[j] = carry;
}

__global__ __launch_bounds__(1024) void scan_totals(
    const int* __restrict__ totals, int KA, int KB, int E2,
    int* __restrict__ offA, int* __restrict__ offB)
{
  __shared__ int buf[1024];
  int t = threadIdx.x;
  int v = (t < KA) ? totals[t] : 0;
  buf[t] = v; __syncthreads();
  #pragma unroll
  for (int off = 1; off < 1024; off <<= 1) {
    int u = (t >= off) ? buf[t - off] : 0;
    __syncthreads(); buf[t] += u; __syncthreads();
  }
  if (t < KA) offA[t] = buf[t] - v;
  if (t == 0) offA[KA] = E2;
  __syncthreads();
  int v2 = (t < KB) ? totals[KA + t] : 0;
  buf[t] = v2; __syncthreads();
  #pragma unroll
  for (int off = 1; off < 1024; off <<= 1) {
    int u = (t >= off) ? buf[t - off] : 0;
    __syncthreads(); buf[t] += u; __syncthreads();
  }
  if (t < KB) offB[t] = buf[t] - v2;
  if (t == 0) offB[KB] = E2;
}

// partition into bucket-contiguous segments. word = other | (key << 16);
// bucket recovered as w >> (16+BSH) (no search). blockIdx.y selects pass.
__global__ __launch_bounds__(256) void partition_edges(
    const int* __restrict__ src, const int* __restrict__ dst, int E, int NL,
    const int* __restrict__ histA, const int* __restrict__ offA,
    const int* __restrict__ histB, const int* __restrict__ offB,
    unsigned int* __restrict__ partA, unsigned int* __restrict__ partB,
    int KA, int KB, int B)
{
  __shared__ unsigned int stage[CHUNK];  // 16 KB
  __shared__ int lbase[KMAX];
  __shared__ int lcur[KMAX];
  __shared__ int gbase[KMAX];
  int tid = threadIdx.x, bid = blockIdx.x;
  int pass = blockIdx.y;
  const int K = pass ? KB : KA;
  const int* hist = pass ? histB : histA;
  const int* off  = pass ? offB : offA;
  unsigned int* out = pass ? partB : partA;

  int base = bid * CHUNK;
  int E2 = E + NL;
  int lim = base + CHUNK < E2 ? base + CHUNK : E2;
  int cnt = lim - base;

  for (int i = tid; i < K; i += 256) lbase[i] = 0;
  __syncthreads();
  for (int i = base + tid; i < lim; i += 256) {
    int s, d;
    if (i < E) { s = src[i]; d = dst[i]; } else { s = d = i - E; }
    int key = pass ? s : d;
    atomicAdd(&lbase[key >> BSH], 1);
  }
  __syncthreads();
  if (tid < 64) {                      // wave-0 exclusive scan over K counts
    int carry = 0;
    for (int c0 = 0; c0 < K; c0 += 64) {
      int c = c0 + tid;
      int v = (c < K) ? lbase[c] : 0;
      int inc = v;
      #pragma unroll
      for (int o = 1; o < 64; o <<= 1) {
        int u = __shfl_up(inc, o, 64);
        if (tid >= o) inc += u;
      }
      if (c < K) lbase[c] = inc - v + carry;
      carry += __shfl(inc, 63, 64);
    }
  }
  __syncthreads();
  for (int k = tid; k < K; k += 256) {
    lcur[k] = lbase[k];
    gbase[k] = off[k] + hist[(size_t)k * B + bid];
  }
  __syncthreads();
  for (int i = base + tid; i < lim; i += 256) {
    int s, d;
    if (i < E) { s = src[i]; d = dst[i]; } else { s = d = i - E; }
    int key = pass ? s : d;
    int val = pass ? d : s;
    int pos = atomicAdd(&lcur[key >> BSH], 1);
    stage[pos] = (unsigned int)val | ((unsigned int)key << 16);
  }
  __syncthreads();
  for (int i = tid; i < cnt; i += 256) {
    unsigned int wv = stage[i];
    int k = wv >> (16 + BSH);
    out[gbase[k] + (i - lbase[k])] = wv;
  }
}

// per-bucket key-sort in LDS -> csr (coalesced write) + row pointers; both passes
__global__ __launch_bounds__(256) void bucket_csr2(
    const unsigned int* __restrict__ partA, const int* __restrict__ offA, int KA, int NA,
    const unsigned int* __restrict__ partB, const int* __restrict__ offB, int KB, int NB,
    int E2, int* __restrict__ csrA, int* __restrict__ rowA,
    int* __restrict__ csrB, int* __restrict__ rowB)
{
  __shared__ int sbuf[CAP];        // 32 KB
  __shared__ int hist[BW + 1];
  __shared__ int cur[BW];
  const unsigned int* part; const int* off; int* csr; int* row; int k, K, N;
  if ((int)blockIdx.x < KA) { k = blockIdx.x; part = partA; off = offA; csr = csrA; row = rowA; K = KA; N = NA; }
  else { k = blockIdx.x - KA; part = partB; off = offB; csr = csrB; row = rowB; K = KB; N = NB; }
  int tid = threadIdx.x;
  int beg = off[k], end = off[k + 1];
  int d0 = k << BSH;
  int width = (BW < N - d0) ? BW : (N - d0);
  int cnt = end - beg;

  for (int i = tid; i <= BW; i += 256) hist[i] = 0;
  __syncthreads();
  for (int i = tid; i < cnt; i += 256)
    atomicAdd(&hist[(part[beg + i] >> 16) & (BW - 1)], 1);
  __syncthreads();
  if (tid == 0) {
    int run = 0;
    for (int j = 0; j < width; ++j) { int c = hist[j]; hist[j] = run; run += c; }
    hist[width] = run;
  }
  __syncthreads();
  if (tid < width) { cur[tid] = hist[tid]; row[d0 + tid] = beg + hist[tid]; }
  if (k == K - 1 && tid == 0) row[N] = E2;
  __syncthreads();
  if (cnt <= CAP) {
    for (int i = tid; i < cnt; i += 256) {
      unsigned int wv = part[beg + i];
      int pos = atomicAdd(&cur[(wv >> 16) & (BW - 1)], 1);
      sbuf[pos] = wv & 0xFFFF;
    }
    __syncthreads();
    for (int i = tid; i < cnt; i += 256) csr[beg + i] = sbuf[i];
  } else {
    for (int i = tid; i < cnt; i += 256) {   // fallback, never for uniform data
      unsigned int wv = part[beg + i];
      int pos = atomicAdd(&cur[(wv >> 16) & (BW - 1)], 1);
      csr[beg + pos] = wv & 0xFFFF;
    }
  }
}

// ---------------- message: one wave per dst, weights computed once/edge ------
__device__ __forceinline__ float lrelu_clamp(float a) {
  a = (a > 0.f) ? a : 0.2f * a;
  return fminf(a, 43.f);
}
__device__ __forceinline__ float bcastf(float v, int l) {
  return __int_as_float(__builtin_amdgcn_readlane(__float_as_int(v), l));
}

__global__ __launch_bounds__(256) void csr_message3(
    const int* __restrict__ rowA, const int* __restrict__ csrA,
    const float* __restrict__ lsA, const float* __restrict__ ldA,
    const __hip_bfloat16* __restrict__ xsA, float* __restrict__ outA, int NdA,
    const int* __restrict__ rowB, const int* __restrict__ csrB,
    const float* __restrict__ lsB, const float* __restrict__ ldB,
    const __hip_bfloat16* __restrict__ xsB, float* __restrict__ outB, int NdB,
    const float* __restrict__ bias, int blocksA)
{
  const int* row; const int* csr_src; const float* logit_s; const float* logit_d;
  const __hip_bfloat16* xs; float* out; int Nd, blk;
  if ((int)blockIdx.x < blocksA) { row = rowA; csr_src = csrA; logit_s = lsA; logit_d = ldA; xs = xsA; out = outA; Nd = NdA; blk = blockIdx.x; }
  else { row = rowB; csr_src = csrB; logit_s = lsB; logit_d = ldB; xs = xsB; out = outB; Nd = NdB; blk = blockIdx.x - blocksA; }

  int d = blk * 4 + (threadIdx.x >> 6);
  if (d >= Nd) return;
  int lane = threadIdx.x & 63;
  int h = lane >> 5;
  int beg = row[d], end = row[d + 1];
  float ld0 = logit_d[d * 2 + 0], ld1 = logit_d[d * 2 + 1];

  float acc = 0.f, s0 = 0.f, s1 = 0.f;
  for (int t0 = beg; t0 < end; t0 += 64) {
    int tc = end - t0; tc = (tc < 64) ? tc : 64;
    // each lane computes ONE edge's weight pair (also accumulates denominator)
    int sv = 0; float e0 = 0.f, e1 = 0.f;
    if (lane < tc) {
      sv = csr_src[t0 + lane];
      float2 l2 = ((const float2*)logit_s)[sv];
      e0 = exp2f(lrelu_clamp(l2.x + ld0));
      e1 = exp2f(lrelu_clamp(l2.y + ld1));
    }
    s0 += e0; s1 += e1;
    // broadcast loop: readlane (SGPR broadcast) + gather + fma
    int j = 0;
    for (; j + 4 <= tc; j += 4) {
      int ja = j, jb = j + 1, jc = j + 2, jd = j + 3;
      int sa = __builtin_amdgcn_readlane(sv, ja);
      int sb = __builtin_amdgcn_readlane(sv, jb);
      int sc = __builtin_amdgcn_readlane(sv, jc);
      int sd = __builtin_amdgcn_readlane(sv, jd);
      float xa = __bfloat162float(xs[(size_t)sa * HC + lane]);
      float xb = __bfloat162float(xs[(size_t)sb * HC + lane]);
      float xc = __bfloat162float(xs[(size_t)sc * HC + lane]);
      float xd = __bfloat162float(xs[(size_t)sd * HC + lane]);
      float wa = h ? bcastf(e1, ja) : bcastf(e0, ja);
      float wb = h ? bcastf(e1, jb) : bcastf(e0, jb);
      float wc = h ? bcastf(e1, jc) : bcastf(e0, jc);
      float wd = h ? bcastf(e1, jd) : bcastf(e0, jd);
      acc = fmaf(wa, xa, acc);
      acc = fmaf(wb, xb, acc);
      acc = fmaf(wc, xc, acc);
      acc = fmaf(wd, xd, acc);
    }
    for (; j < tc; ++j) {
      int sa = __builtin_amdgcn_readlane(sv, j);
      float xa = __bfloat162float(xs[(size_t)sa * HC + lane]);
      float wa = h ? bcastf(e1, j) : bcastf(e0, j);
      acc = fmaf(wa, xa, acc);
    }
  }
  // reduce denominators across the wave
  #pragma unroll
  for (int off = 32; off > 0; off >>= 1) {
    s0 += __shfl_xor(s0, off, 64);
    s1 += __shfl_xor(s1, off, 64);
  }
  float inv = 1.f / ((h ? s1 : s0) + 1e-16f);
  out[(size_t)d * HC + lane] = acc * inv + bias[lane];
}

extern "C" void kernel_launch(void* const* d_in, const int* in_sizes, int n_in,
                              void* d_out, int out_size, void* d_ws, size_t ws_size,
                              hipStream_t stream)
{
  const float* h_x   = (const float*)d_in[0];
  const float* t_x   = (const float*)d_in[1];
  const int*   edge  = (const int*)d_in[2];
  const float* W_src = (const float*)d_in[3];
  const float* W_dst = (const float*)d_in[4];
  const float* att_s = (const float*)d_in[5];
  const float* att_d = (const float*)d_in[6];
  const float* bias  = (const float*)d_in[7];

  int NH = in_sizes[0] / DD;
  int NT = in_sizes[1] / DD;
  int E  = in_sizes[2] / 2;
  int NL = (NH < NT) ? NH : NT;
  int E2 = E + NL;
  const int* srcA = edge;       // row 0 (h index)
  const int* dstA = edge + E;   // row 1 (t index)

  int KA = (NT + BW - 1) >> BSH;   // pass A buckets (over t / dst)
  int KB = (NH + BW - 1) >> BSH;   // pass B buckets (over h / src)
  int B  = (E2 + CHUNK - 1) / CHUNK;

  char* w = (char*)d_ws;
  size_t used = 0;
  auto alloc = [&](size_t bytes) {
    char* p = w + used; used = (used + bytes + 255) & ~(size_t)255; return p;
  };
  __hip_bfloat16* xsA = (__hip_bfloat16*)alloc((size_t)NH * HC * 2);
  __hip_bfloat16* xsB = (__hip_bfloat16*)alloc((size_t)NT * HC * 2);
  float* lsA  = (float*)alloc((size_t)NH * 2 * 4);
  float* ldB  = (float*)alloc((size_t)NH * 2 * 4);
  float* lsB  = (float*)alloc((size_t)NT * 2 * 4);
  float* ldA  = (float*)alloc((size_t)NT * 2 * 4);
  int* histA  = (int*)alloc((size_t)KA * B * 4);
  int* histB  = (int*)alloc((size_t)KB * B * 4);
  int* totals = (int*)alloc((size_t)(KA + KB) * 4);
  int* offA   = (int*)alloc((size_t)(KA + 1) * 4);
  int* offB   = (int*)alloc((size_t)(KB + 1) * 4);
  int* rowT   = (int*)alloc((size_t)(NT + 1) * 4);
  int* rowH   = (int*)alloc((size_t)(NH + 1) * 4);
  unsigned int* partA = (unsigned int*)alloc((size_t)E2 * 4);
  unsigned int* partB = (unsigned int*)alloc((size_t)E2 * 4);
  int* csrT   = (int*)alloc((size_t)E2 * 4);
  int* csrH   = (int*)alloc((size_t)E2 * 4);

  float* out   = (float*)d_out;              // (h_rep [NH,64], t_rep [NT,64])
  float* out_h = out;
  float* out_t = out + (size_t)NH * HC;

  int bH = (NH + NPB - 1) / NPB, bT = (NT + NPB - 1) / NPB;
  node_transform2<<<bH + bT, 256, 0, stream>>>(
      h_x, t_x, W_src, W_dst, att_s, att_d,
      xsA, xsB, lsA, ldB, lsB, ldA, NH, NT, bH);

  hist_both<<<B, 256, 0, stream>>>(srcA, dstA, E, NL, histA, histB, KA, KB, B);
  scan_hist<<<(KA + KB + 3) / 4, 256, 0, stream>>>(histA, KA, histB, KB, B, totals);
  scan_totals<<<1, 1024, 0, stream>>>(totals, KA, KB, E2, offA, offB);
  partition_edges<<<dim3(B, 2), 256, 0, stream>>>(
      srcA, dstA, E, NL, histA, offA, histB, offB, partA, partB, KA, KB, B);
  bucket_csr2<<<KA + KB, 256, 0, stream>>>(partA, offA, KA, NT, partB, offB, KB, NH,
                                           E2, csrT, rowT, csrH, rowH);

  // pass A: src=h, dst=t -> t_rep ; pass B: src=t, dst=h -> h_rep
  int gA = (NT + 3) / 4, gB = (NH + 3) / 4;
  csr_message3<<<gA + gB, 256, 0, stream>>>(
      rowT, csrT, lsA, ldA, xsA, out_t, NT,
      rowH, csrH, lsB, ldB, xsB, out_h, NH, bias, gA);
}